// Round 1
// baseline (43.337 us; speedup 1.0000x reference)
//
#include <hip/hip_runtime.h>

#define T_LEN  4096
#define N_MODES 64
#define CHUNK  128
#define NCHUNK (T_LEN / CHUNK)   // 32
#define SUB    16                // transpose-reduce block

// ---- Phase 1: per-chunk local recurrence from zero init; emit end state ----
__global__ __launch_bounds__(256) void ssm_phase1(
    const float* __restrict__ u, const float* __restrict__ rho,
    const float* __restrict__ theta, const float* __restrict__ br,
    const float* __restrict__ bi, float2* __restrict__ xend) {
  __shared__ float us[4][CHUNK];
  const int wv = threadIdx.x >> 6;
  const int lane = threadIdx.x & 63;
  const int wid = blockIdx.x * 4 + wv;        // row * NCHUNK + chunk
  const int row = wid >> 5;                   // NCHUNK == 32
  const int chunk = wid & (NCHUNK - 1);

  const float rh = rho[lane], th = theta[lane];
  const float r = expf(-log1pf(expf(rh)));
  const float lre = r * cosf(th), lim = r * sinf(th);
  const float bre = br[lane], bim = bi[lane];

  const float* up = u + (size_t)row * T_LEN + chunk * CHUNK;
  us[wv][lane] = up[lane];
  us[wv][lane + 64] = up[lane + 64];
  __syncthreads();

  float xr = 0.f, xi = 0.f;
#pragma unroll 16
  for (int t = 0; t < CHUNK; ++t) {
    const float ut = us[wv][t];
    const float nr = fmaf(lre, xr, fmaf(-lim, xi, bre * ut));
    const float ni = fmaf(lre, xi, fmaf(lim, xr, bim * ut));
    xr = nr; xi = ni;
  }
  xend[(size_t)wid * 64 + lane] = make_float2(xr, xi);
}

// ---- Phase 2: sequential combine across chunks; emit per-chunk entry state ----
__global__ __launch_bounds__(256) void ssm_phase2(
    const float2* __restrict__ xend, const float* __restrict__ rho,
    const float* __restrict__ theta, float2* __restrict__ carry) {
  const int lane = threadIdx.x & 63;
  const int row = blockIdx.x * 4 + (threadIdx.x >> 6);

  const float rh = rho[lane], th = theta[lane];
  const float r = expf(-log1pf(expf(rh)));
  float pr = r * cosf(th), pi = r * sinf(th);
  // lam^CHUNK, CHUNK = 128 = 2^7 -> 7 complex squarings
#pragma unroll
  for (int k = 0; k < 7; ++k) {
    const float nr = pr * pr - pi * pi;
    const float ni = 2.f * pr * pi;
    pr = nr; pi = ni;
  }

  float cr_ = 0.f, ci_ = 0.f;
  for (int j = 0; j < NCHUNK; ++j) {
    const size_t idx = ((size_t)row * NCHUNK + j) * 64 + lane;
    carry[idx] = make_float2(cr_, ci_);
    const float2 e = xend[idx];
    const float nr = fmaf(pr, cr_, fmaf(-pi, ci_, e.x));
    const float ni = fmaf(pr, ci_, fmaf(pi, cr_, e.y));
    cr_ = nr; ci_ = ni;
  }
}

// ---- Phase 3: re-run chunks from true entry state; produce y via LDS transpose-reduce ----
__global__ __launch_bounds__(256) void ssm_phase3(
    const float* __restrict__ u, const float2* __restrict__ carry,
    const float* __restrict__ rho, const float* __restrict__ theta,
    const float* __restrict__ br, const float* __restrict__ bi,
    const float* __restrict__ cr, const float* __restrict__ ci,
    float* __restrict__ out) {
  __shared__ float us[4][CHUNK];
  __shared__ float pb[4][SUB][64];
  const int wv = threadIdx.x >> 6;
  const int lane = threadIdx.x & 63;
  const int wid = blockIdx.x * 4 + wv;
  const int row = wid >> 5;
  const int chunk = wid & (NCHUNK - 1);

  const float rh = rho[lane], th = theta[lane];
  const float r = expf(-log1pf(expf(rh)));
  const float lre = r * cosf(th), lim = r * sinf(th);
  const float bre = br[lane], bim = bi[lane];
  const float cre = cr[lane], cim = ci[lane];

  const float* up = u + (size_t)row * T_LEN + chunk * CHUNK;
  us[wv][lane] = up[lane];
  us[wv][lane + 64] = up[lane + 64];

  const float2 x0 = carry[(size_t)wid * 64 + lane];
  float xr = x0.x, xi = x0.y;
  __syncthreads();

  const int tt = lane & (SUB - 1);
  const int q = lane >> 4;   // 4 groups of 16 modes each
  float* orow = out + (size_t)row * T_LEN + chunk * CHUNK;

  for (int sb = 0; sb < CHUNK / SUB; ++sb) {
#pragma unroll
    for (int t = 0; t < SUB; ++t) {
      const float ut = us[wv][sb * SUB + t];
      const float nr = fmaf(lre, xr, fmaf(-lim, xi, bre * ut));
      const float ni = fmaf(lre, xi, fmaf(lim, xr, bim * ut));
      xr = nr; xi = ni;
      // XOR-ish rotate swizzle: p[t][n] stored at [t][(n+t)&63] -> 2-way banks max
      pb[wv][t][(lane + t) & 63] = fmaf(cre, xr, cim * xi);
    }
    __syncthreads();
    float s = 0.f;
#pragma unroll
    for (int n = 0; n < 16; ++n) {
      const int m = q * 16 + n;
      s += pb[wv][tt][(m + tt) & 63];
    }
    s += __shfl_xor(s, 16);
    s += __shfl_xor(s, 32);
    if (lane < SUB) orow[sb * SUB + tt] = s;
    __syncthreads();  // pb reused next sub-block
  }
}

extern "C" void kernel_launch(void* const* d_in, const int* in_sizes, int n_in,
                              void* d_out, int out_size, void* d_ws, size_t ws_size,
                              hipStream_t stream) {
  const float* u     = (const float*)d_in[0];
  const float* rho   = (const float*)d_in[1];
  const float* theta = (const float*)d_in[2];
  const float* br    = (const float*)d_in[3];
  const float* bi    = (const float*)d_in[4];
  const float* cr    = (const float*)d_in[5];
  const float* ci    = (const float*)d_in[6];
  float* out = (float*)d_out;

  const int B = in_sizes[0] / T_LEN;          // 256
  const int nwave = B * NCHUNK;               // 8192

  float2* xend  = (float2*)d_ws;                       // B*NCHUNK*64 float2 = 4 MB
  float2* carry = xend + (size_t)nwave * 64;           // another 4 MB

  ssm_phase1<<<nwave / 4, 256, 0, stream>>>(u, rho, theta, br, bi, xend);
  ssm_phase2<<<B / 4, 256, 0, stream>>>(xend, rho, theta, carry);
  ssm_phase3<<<nwave / 4, 256, 0, stream>>>(u, carry, rho, theta, br, bi, cr, ci, out);
}

// Round 2
// 24.713 us; speedup vs baseline: 1.7536x; 1.7536x over previous
//
#include <hip/hip_runtime.h>
#include <hip/hip_bf16.h>

#define T_LEN 4096
#define PADW  1280
#define ROWW  5504      // PADW + 4096 + 128 tail pad
#define NLAG  10

typedef __attribute__((ext_vector_type(8))) short short8;
typedef __attribute__((ext_vector_type(4))) float f32x4;

static __device__ __forceinline__ unsigned short f2bf(float f) {
  __hip_bfloat16 h = __float2bfloat16(f);
  return *reinterpret_cast<unsigned short*>(&h);
}

// ---- k_d = Re(sum_n conj(c)b * lam^d), one wave per d-index of kz[1344] ----
__global__ __launch_bounds__(256) void k_build(
    const float* __restrict__ rho, const float* __restrict__ theta,
    const float* __restrict__ br, const float* __restrict__ bi,
    const float* __restrict__ cr, const float* __restrict__ ci,
    float* __restrict__ kz) {
  const int lane = threadIdx.x & 63;
  const int i = blockIdx.x * 4 + (threadIdx.x >> 6);   // 0..1343
  const int d = i - 128;                               // kz[128+d] = k_d, d<0 -> 0
  float v = 0.f;
  if (d >= 0) {
    const float logr = -log1pf(expf(rho[lane]));       // log r
    const float rd = expf((float)d * logr);
    const float ang = theta[lane] * (float)d;
    const float brv = br[lane], biv = bi[lane];
    const float crv = cr[lane], civ = ci[lane];
    const float gr = crv * brv + civ * biv;
    const float gi = crv * biv - civ * brv;
    v = rd * (gr * cosf(ang) - gi * sinf(ang));
  }
#pragma unroll
  for (int off = 1; off < 64; off <<= 1) v += __shfl_xor(v, off);
  if (lane == 0) kz[i] = v;
}

// ---- Toeplitz tiles: kt[j][t'][s'] = k[j*128 + t' - s'] as bf16 ----
__global__ __launch_bounds__(256) void ktile_build(const float* __restrict__ kz,
                                                   unsigned short* __restrict__ kt) {
  const int t = blockIdx.x * 256 + threadIdx.x;        // 0..81919
  const int j = t >> 13;
  const int r = (t >> 7) & 63;
  const int s = t & 127;
  const int dd = 128 + j * 128 + r - s;                // in [1,1343]
  kt[t] = f2bf(kz[dd]);
}

// ---- u -> zero-padded bf16 rows of length ROWW ----
__global__ __launch_bounds__(256) void u_convert(const float* __restrict__ u,
                                                 unsigned short* __restrict__ up) {
  const int tid = blockIdx.x * 256 + threadIdx.x;      // 256*688 threads
  const int b = tid / 688;
  const int c8 = (tid - b * 688) * 8;
  const int s0 = c8 - PADW;
  unsigned short o[8];
  if (s0 >= 0 && s0 + 8 <= T_LEN) {
    const float4* p = reinterpret_cast<const float4*>(u + (size_t)b * T_LEN + s0);
    float4 a = p[0], c = p[1];
    o[0] = f2bf(a.x); o[1] = f2bf(a.y); o[2] = f2bf(a.z); o[3] = f2bf(a.w);
    o[4] = f2bf(c.x); o[5] = f2bf(c.y); o[6] = f2bf(c.z); o[7] = f2bf(c.w);
  } else {
#pragma unroll
    for (int e = 0; e < 8; ++e) {
      const int s = s0 + e;
      o[e] = (s >= 0 && s < T_LEN) ? f2bf(u[(size_t)b * T_LEN + s]) : (unsigned short)0;
    }
  }
  *reinterpret_cast<short8*>(up + (size_t)b * ROWW + c8) =
      *reinterpret_cast<const short8*>(o);
}

// ---- banded Toeplitz GEMM: out[64x64 tile] += sum_j U_j(64x128) * KtT_j^T ----
__global__ __launch_bounds__(256) void conv_gemm(
    const unsigned short* __restrict__ up, const unsigned short* __restrict__ kt,
    float* __restrict__ out) {
  __shared__ unsigned short lds[2][2][8192];   // [buf][A=u/B=kt][64][128], 64KB
  const int tid = threadIdx.x;
  const int lane = tid & 63;
  const int w = tid >> 6;
  const int wm = w >> 1, wn = w & 1;
  const int t0 = blockIdx.x * 64;
  const int b0 = blockIdx.y * 64;

  const int lrow = lane >> 4;    // row within 4-row stage group
  const int lc16 = lane & 15;    // 16B chunk within row

  f32x4 acc[2][2] = {};

  // stage one j-block: LDS dest linear (global_load_lds requirement),
  // XOR swizzle folded into the per-lane GLOBAL source address (rule #21).
#define STAGE(buf, j)                                                              \
  {                                                                                \
    const int sb_ = t0 + PADW - (j) * 128;                                         \
    _Pragma("unroll") for (int i_ = 0; i_ < 4; ++i_) {                             \
      const int ii_ = w * 4 + i_;                                                  \
      const int r_ = ii_ * 4 + lrow;                                               \
      const int le_ = (lc16 * 8) ^ ((r_ & 7) << 3);                                \
      __builtin_amdgcn_global_load_lds(                                            \
          (const __attribute__((address_space(1))) void*)(up +                     \
              (size_t)(b0 + r_) * ROWW + sb_ + le_),                               \
          (__attribute__((address_space(3))) void*)&lds[buf][0][ii_ * 512],        \
          16, 0, 0);                                                               \
      __builtin_amdgcn_global_load_lds(                                            \
          (const __attribute__((address_space(1))) void*)(kt + (j) * 8192 +        \
              r_ * 128 + le_),                                                     \
          (__attribute__((address_space(3))) void*)&lds[buf][1][ii_ * 512],        \
          16, 0, 0);                                                               \
    }                                                                              \
  }

  STAGE(0, 0);
  __syncthreads();

#pragma unroll
  for (int j = 0; j < NLAG; ++j) {
    const int cur = j & 1;
    if (j + 1 < NLAG) STAGE(cur ^ 1, j + 1);
    const unsigned short* A = lds[cur][0];
    const unsigned short* Bt = lds[cur][1];
#pragma unroll
    for (int ks = 0; ks < 4; ++ks) {
      short8 af[2], bfr[2];
#pragma unroll
      for (int ft = 0; ft < 2; ++ft) {
        const int r = wm * 32 + ft * 16 + (lane & 15);
        const int pe = (ks * 32 + (lane >> 4) * 8) ^ ((r & 7) << 3);
        af[ft] = *reinterpret_cast<const short8*>(&A[r * 128 + pe]);
      }
#pragma unroll
      for (int fn = 0; fn < 2; ++fn) {
        const int r = wn * 32 + fn * 16 + (lane & 15);
        const int pe = (ks * 32 + (lane >> 4) * 8) ^ ((r & 7) << 3);
        bfr[fn] = *reinterpret_cast<const short8*>(&Bt[r * 128 + pe]);
      }
#pragma unroll
      for (int ft = 0; ft < 2; ++ft)
#pragma unroll
        for (int fn = 0; fn < 2; ++fn)
          acc[ft][fn] = __builtin_amdgcn_mfma_f32_16x16x32_bf16(
              af[ft], bfr[fn], acc[ft][fn], 0, 0, 0);
    }
    __syncthreads();   // drains vmcnt (stage j+1 landed) + lgkmcnt, then barrier
  }

#pragma unroll
  for (int ft = 0; ft < 2; ++ft)
#pragma unroll
    for (int fn = 0; fn < 2; ++fn)
#pragma unroll
      for (int reg = 0; reg < 4; ++reg) {
        const int row = b0 + wm * 32 + ft * 16 + (lane >> 4) * 4 + reg;
        const int col = t0 + wn * 32 + fn * 16 + (lane & 15);
        out[(size_t)row * T_LEN + col] = acc[ft][fn][reg];
      }
#undef STAGE
}

extern "C" void kernel_launch(void* const* d_in, const int* in_sizes, int n_in,
                              void* d_out, int out_size, void* d_ws, size_t ws_size,
                              hipStream_t stream) {
  const float* u     = (const float*)d_in[0];
  const float* rho   = (const float*)d_in[1];
  const float* theta = (const float*)d_in[2];
  const float* br    = (const float*)d_in[3];
  const float* bi    = (const float*)d_in[4];
  const float* cr    = (const float*)d_in[5];
  const float* ci    = (const float*)d_in[6];
  float* out = (float*)d_out;

  char* ws = (char*)d_ws;
  float* kz            = (float*)ws;                       // 1344 f32
  unsigned short* kt   = (unsigned short*)(ws + 8192);     // 10*64*128 bf16 = 160KB
  unsigned short* upad = (unsigned short*)(ws + 262144);   // 256*5504 bf16 = 2.75MB

  k_build<<<336, 256, 0, stream>>>(rho, theta, br, bi, cr, ci, kz);
  u_convert<<<688, 256, 0, stream>>>(u, upad);
  ktile_build<<<320, 256, 0, stream>>>(kz, kt);
  conv_gemm<<<dim3(64, 4), 256, 0, stream>>>(upad, kt, out);
}

// Round 3
// 16.103 us; speedup vs baseline: 2.6912x; 1.5347x over previous
//
#include <hip/hip_runtime.h>
#include <hip/hip_bf16.h>

#define T_LEN 4096
#define PADW  1280
#define ROWW  5504      // PADW + 4096 + 128 tail pad
#define NLAG  10
#define KBLK  336       // 1344 waves: d = wid-127 in [-127, 1216]
#define UBLK  688

typedef __attribute__((ext_vector_type(8))) short short8;
typedef __attribute__((ext_vector_type(4))) float f32x4;

static __device__ __forceinline__ unsigned short f2bf(float f) {
  __hip_bfloat16 h = __float2bfloat16(f);
  return *reinterpret_cast<unsigned short*>(&h);
}

// ---- fused prep: blocks [0,KBLK) build kt via per-diagonal scatter;
//      blocks [KBLK, KBLK+UBLK) zero-pad/convert u to bf16 ----
__global__ __launch_bounds__(256) void prep(
    const float* __restrict__ u, const float* __restrict__ rho,
    const float* __restrict__ theta, const float* __restrict__ br,
    const float* __restrict__ bi, const float* __restrict__ cr,
    const float* __restrict__ ci, unsigned short* __restrict__ kt,
    unsigned short* __restrict__ up) {
  const int blk = blockIdx.x;
  if (blk < KBLK) {
    // one wave per lag d; butterfly sum lands in ALL lanes, then each lane r
    // scatters kt[j][r][r-delta] for the (<=2) tiles whose band contains d.
    const int lane = threadIdx.x & 63;
    const int wid = blk * 4 + (threadIdx.x >> 6);
    const int d = wid - 127;                  // [-127, 1216]
    float v = 0.f;
    if (d >= 0) {                             // wave-uniform branch
      const float logr = -log1pf(expf(rho[lane]));
      const float rd = expf((float)d * logr);
      const float ang = theta[lane] * (float)d;
      const float brv = br[lane], biv = bi[lane];
      const float crv = cr[lane], civ = ci[lane];
      const float gr = crv * brv + civ * biv;
      const float gi = crv * biv - civ * brv;
      v = rd * (gr * cosf(ang) - gi * sinf(ang));
#pragma unroll
      for (int off = 1; off < 64; off <<= 1) v += __shfl_xor(v, off);
    }
    const unsigned short kv = f2bf(v);
#pragma unroll
    for (int j = 0; j < NLAG; ++j) {
      const int delta = d - j * 128;          // r - s on this tile
      if (delta >= -127 && delta <= 63) {
        const int s = lane - delta;
        if (s >= 0 && s < 128)
          kt[(j * 64 + lane) * 128 + s] = kv;
      }
    }
  } else {
    const int tid = (blk - KBLK) * 256 + threadIdx.x;  // < 176128
    const int b = tid / UBLK;
    const int c8 = (tid - b * UBLK) * 8;
    const int s0 = c8 - PADW;
    unsigned short o[8];
    if (s0 >= 0 && s0 + 8 <= T_LEN) {
      const float4* p = reinterpret_cast<const float4*>(u + (size_t)b * T_LEN + s0);
      float4 a = p[0], c = p[1];
      o[0] = f2bf(a.x); o[1] = f2bf(a.y); o[2] = f2bf(a.z); o[3] = f2bf(a.w);
      o[4] = f2bf(c.x); o[5] = f2bf(c.y); o[6] = f2bf(c.z); o[7] = f2bf(c.w);
    } else {
#pragma unroll
      for (int e = 0; e < 8; ++e) {
        const int s = s0 + e;
        o[e] = (s >= 0 && s < T_LEN) ? f2bf(u[(size_t)b * T_LEN + s]) : (unsigned short)0;
      }
    }
    *reinterpret_cast<short8*>(up + (size_t)b * ROWW + c8) =
        *reinterpret_cast<const short8*>(o);
  }
}

// ---- banded Toeplitz GEMM, depth-2 prefetch, counted vmcnt (never 0 mid-loop) ----
__global__ __launch_bounds__(256) void conv_gemm(
    const unsigned short* __restrict__ up, const unsigned short* __restrict__ kt,
    float* __restrict__ out) {
  __shared__ unsigned short lds[3][2][8192];   // 3 bufs x {A=u, B=kt} x 16KB = 96KB
  const int tid = threadIdx.x;
  const int lane = tid & 63;
  const int w = tid >> 6;
  const int wm = w >> 1, wn = w & 1;

  // XCD-chunked swizzle: consecutive t-tiles (95% overlapping u bands) share an L2
  const int bid = blockIdx.x;                  // 256 blocks, 256%8==0 -> bijective
  const int swz = (bid & 7) * 32 + (bid >> 3);
  const int t0 = (swz & 63) * 64;
  const int b0 = (swz >> 6) * 64;

  const int lrow = lane >> 4;
  const int lc16 = lane & 15;

  f32x4 acc[2][2] = {};

#define STAGE(buf, j)                                                              \
  {                                                                                \
    const int sb_ = t0 + PADW - (j) * 128;                                         \
    _Pragma("unroll") for (int i_ = 0; i_ < 4; ++i_) {                             \
      const int ii_ = w * 4 + i_;                                                  \
      const int r_ = ii_ * 4 + lrow;                                               \
      const int le_ = (lc16 * 8) ^ ((r_ & 7) << 3);                                \
      __builtin_amdgcn_global_load_lds(                                            \
          (const __attribute__((address_space(1))) void*)(up +                     \
              (size_t)(b0 + r_) * ROWW + sb_ + le_),                               \
          (__attribute__((address_space(3))) void*)&lds[buf][0][ii_ * 512],        \
          16, 0, 0);                                                               \
      __builtin_amdgcn_global_load_lds(                                            \
          (const __attribute__((address_space(1))) void*)(kt + (j) * 8192 +        \
              r_ * 128 + le_),                                                     \
          (__attribute__((address_space(3))) void*)&lds[buf][1][ii_ * 512],        \
          16, 0, 0);                                                               \
    }                                                                              \
  }

  STAGE(0, 0);
  STAGE(1, 1);

#pragma unroll
  for (int j = 0; j < NLAG; ++j) {
    // own stage-j loads done (8 newer may stay in flight); barrier makes it global
    if (j < NLAG - 1) asm volatile("s_waitcnt vmcnt(8)" ::: "memory");
    else              asm volatile("s_waitcnt vmcnt(0)" ::: "memory");
    asm volatile("s_barrier" ::: "memory");
    // stage j+2 into buf (j+2)%3 == (j-1)%3: last read at compute j-1, which
    // precedes barrier j in every wave's program order -> race-free.
    if (j + 2 < NLAG) STAGE((j + 2) % 3, j + 2);

    const unsigned short* A  = lds[j % 3][0];
    const unsigned short* Bt = lds[j % 3][1];
#pragma unroll
    for (int ks = 0; ks < 4; ++ks) {
      short8 af[2], bfr[2];
#pragma unroll
      for (int ft = 0; ft < 2; ++ft) {
        const int r = wm * 32 + ft * 16 + (lane & 15);
        const int pe = (ks * 32 + (lane >> 4) * 8) ^ ((r & 7) << 3);
        af[ft] = *reinterpret_cast<const short8*>(&A[r * 128 + pe]);
      }
#pragma unroll
      for (int fn = 0; fn < 2; ++fn) {
        const int r = wn * 32 + fn * 16 + (lane & 15);
        const int pe = (ks * 32 + (lane >> 4) * 8) ^ ((r & 7) << 3);
        bfr[fn] = *reinterpret_cast<const short8*>(&Bt[r * 128 + pe]);
      }
#pragma unroll
      for (int ft = 0; ft < 2; ++ft)
#pragma unroll
        for (int fn = 0; fn < 2; ++fn)
          acc[ft][fn] = __builtin_amdgcn_mfma_f32_16x16x32_bf16(
              af[ft], bfr[fn], acc[ft][fn], 0, 0, 0);
    }
  }

#pragma unroll
  for (int ft = 0; ft < 2; ++ft)
#pragma unroll
    for (int fn = 0; fn < 2; ++fn)
#pragma unroll
      for (int reg = 0; reg < 4; ++reg) {
        const int row = b0 + wm * 32 + ft * 16 + (lane >> 4) * 4 + reg;
        const int col = t0 + wn * 32 + fn * 16 + (lane & 15);
        out[(size_t)row * T_LEN + col] = acc[ft][fn][reg];
      }
#undef STAGE
}

extern "C" void kernel_launch(void* const* d_in, const int* in_sizes, int n_in,
                              void* d_out, int out_size, void* d_ws, size_t ws_size,
                              hipStream_t stream) {
  const float* u     = (const float*)d_in[0];
  const float* rho   = (const float*)d_in[1];
  const float* theta = (const float*)d_in[2];
  const float* br    = (const float*)d_in[3];
  const float* bi    = (const float*)d_in[4];
  const float* cr    = (const float*)d_in[5];
  const float* ci    = (const float*)d_in[6];
  float* out = (float*)d_out;

  char* ws = (char*)d_ws;
  unsigned short* kt   = (unsigned short*)ws;              // 10*64*128 bf16 = 160KB
  unsigned short* upad = (unsigned short*)(ws + 262144);   // 256*5504 bf16 = 2.75MB

  prep<<<KBLK + UBLK, 256, 0, stream>>>(u, rho, theta, br, bi, cr, ci, kt, upad);
  conv_gemm<<<256, 256, 0, stream>>>(upad, kt, out);
}